// Round 19
// baseline (407.541 us; speedup 1.0000x reference)
//
#include <hip/hip_runtime.h>
#include <cstdint>
#include <cstddef>

#define NB 32
#define NN 1024
#define ND 256
#define KNNK 16

typedef __attribute__((ext_vector_type(8))) short bf16x8;
typedef __attribute__((ext_vector_type(4))) float f32x4;
typedef __attribute__((ext_vector_type(4))) short short4v;

// Round-to-nearest-even bf16 split (identical arithmetic to v12-v18).
__device__ __forceinline__ void bf16_split(float v, unsigned short& h,
                                           unsigned short& l) {
    uint32_t u  = __float_as_uint(v);
    uint32_t hi = (u + 0x7fffu + ((u >> 16) & 1u)) >> 16;
    float    hf = __uint_as_float(hi << 16);
    uint32_t g  = __float_as_uint(v - hf);
    uint32_t lo = (g + 0x7fffu + ((g >> 16) & 1u)) >> 16;
    h = (unsigned short)hi;
    l = (unsigned short)lo;
}

// Fragment-tiled plane layout (shorts):
//   plane[rt][c][lh][lr][i] ; rt = flat_row>>4, c = e>>5, lh = (e>>3)&3,
//   lr = flat_row&15, i = e&7 ; linear: rt*4096 + c*512 + lh*128 + lr*8 + i

// ---------------------------------------------------------------------------
// Kernel A v19: fused pos-add + dual projection -> 4 bf16 planes.
// Block computes an e-tile PAIR for both Q and K (grid 1024, bp in {0,1}):
// H staged once per chunk feeds 4 acc arrays -> staging/barriers per FMA
// halved, x re-read 4x -> 2x. Per-element fmaf chain identical to v16-v18
// -> bit-identical planes (absmax must stay exactly 0.01257324).
// ---------------------------------------------------------------------------
__global__ __launch_bounds__(256) void proj_kernel(
    const float* __restrict__ x, const float* __restrict__ pos,
    const float* __restrict__ wq, const float* __restrict__ bq,
    const float* __restrict__ wk, const float* __restrict__ bk,
    unsigned short* __restrict__ Qh, unsigned short* __restrict__ Ql,
    unsigned short* __restrict__ Kh, unsigned short* __restrict__ Kl)
{
    __shared__ __align__(16) float Hs [16][68];
    __shared__ __align__(16) float Wq0[16][68];
    __shared__ __align__(16) float Wq1[16][68];
    __shared__ __align__(16) float Wk0[16][68];
    __shared__ __align__(16) float Wk1[16][68];

    const int tid = threadIdx.x;
    const int tx = tid & 15;          // e microtile index
    const int ty = tid >> 4;          // row microtile index
    const int bm = blockIdx.x >> 1;   // 0..511 row tiles
    const int bp = blockIdx.x & 1;    // e-tile pair selector
    const int rowBase = bm << 6;      // flattened b*1024 + n
    const int n0 = rowBase & 1023;
    const int e0 = bp << 7;           // 0 or 128; tiles e0 and e0+64

    const int sr = tid >> 2;          // 0..63
    const int sd = (tid & 3) << 2;    // 0,4,8,12

    float accQ0[4][4], accQ1[4][4], accK0[4][4], accK1[4][4];
    #pragma unroll
    for (int i = 0; i < 4; ++i)
        #pragma unroll
        for (int j = 0; j < 4; ++j) {
            accQ0[i][j] = 0.0f; accQ1[i][j] = 0.0f;
            accK0[i][j] = 0.0f; accK1[i][j] = 0.0f;
        }

    #pragma unroll 1
    for (int dc = 0; dc < 256; dc += 16) {
        const float4 xv  = *(const float4*)&x  [(size_t)(rowBase + sr) * 256 + dc + sd];
        const float4 pv  = *(const float4*)&pos[(size_t)(n0 + sr) * 256 + dc + sd];
        const float4 q0v = *(const float4*)&wq [(size_t)(e0 + sr) * 256 + dc + sd];
        const float4 q1v = *(const float4*)&wq [(size_t)(e0 + 64 + sr) * 256 + dc + sd];
        const float4 k0v = *(const float4*)&wk [(size_t)(e0 + sr) * 256 + dc + sd];
        const float4 k1v = *(const float4*)&wk [(size_t)(e0 + 64 + sr) * 256 + dc + sd];
        __syncthreads();
        Hs [sd + 0][sr] = xv.x + pv.x;
        Hs [sd + 1][sr] = xv.y + pv.y;
        Hs [sd + 2][sr] = xv.z + pv.z;
        Hs [sd + 3][sr] = xv.w + pv.w;
        Wq0[sd + 0][sr] = q0v.x; Wq0[sd + 1][sr] = q0v.y;
        Wq0[sd + 2][sr] = q0v.z; Wq0[sd + 3][sr] = q0v.w;
        Wq1[sd + 0][sr] = q1v.x; Wq1[sd + 1][sr] = q1v.y;
        Wq1[sd + 2][sr] = q1v.z; Wq1[sd + 3][sr] = q1v.w;
        Wk0[sd + 0][sr] = k0v.x; Wk0[sd + 1][sr] = k0v.y;
        Wk0[sd + 2][sr] = k0v.z; Wk0[sd + 3][sr] = k0v.w;
        Wk1[sd + 0][sr] = k1v.x; Wk1[sd + 1][sr] = k1v.y;
        Wk1[sd + 2][sr] = k1v.z; Wk1[sd + 3][sr] = k1v.w;
        __syncthreads();
        #pragma unroll
        for (int d = 0; d < 16; ++d) {
            const float4 rv  = *(const float4*)&Hs [d][ty << 2];
            const float4 q0e = *(const float4*)&Wq0[d][tx << 2];
            const float4 q1e = *(const float4*)&Wq1[d][tx << 2];
            const float4 k0e = *(const float4*)&Wk0[d][tx << 2];
            const float4 k1e = *(const float4*)&Wk1[d][tx << 2];
            const float a4[4]  = {rv.x, rv.y, rv.z, rv.w};
            const float q04[4] = {q0e.x, q0e.y, q0e.z, q0e.w};
            const float q14[4] = {q1e.x, q1e.y, q1e.z, q1e.w};
            const float k04[4] = {k0e.x, k0e.y, k0e.z, k0e.w};
            const float k14[4] = {k1e.x, k1e.y, k1e.z, k1e.w};
            #pragma unroll
            for (int i = 0; i < 4; ++i)
                #pragma unroll
                for (int j = 0; j < 4; ++j) {
                    accQ0[i][j] = fmaf(a4[i], q04[j], accQ0[i][j]);
                    accQ1[i][j] = fmaf(a4[i], q14[j], accQ1[i][j]);
                    accK0[i][j] = fmaf(a4[i], k04[j], accK0[i][j]);
                    accK1[i][j] = fmaf(a4[i], k14[j], accK1[i][j]);
                }
        }
    }

    // bias + fragment-tiled plane stores, per e-tile
    #pragma unroll
    for (int t = 0; t < 2; ++t) {
        const int et0 = e0 + (t << 6);
        const float4 bq4 = *(const float4*)&bq[et0 + (tx << 2)];
        const float4 bk4 = *(const float4*)&bk[et0 + (tx << 2)];
        const float bbq[4] = {bq4.x, bq4.y, bq4.z, bq4.w};
        const float bbk[4] = {bk4.x, bk4.y, bk4.z, bk4.w};

        const int e_lo = et0 + (tx << 2);
        const int c0   = e_lo >> 5;
        const int lh0  = (e_lo >> 3) & 3;
        const int i0   = e_lo & 7;                 // 0 or 4
        #pragma unroll
        for (int i = 0; i < 4; ++i) {
            const int row = rowBase + (ty << 2) + i;
            const size_t addr = (size_t)(row >> 4) * 4096 + c0 * 512 + lh0 * 128
                              + (size_t)(row & 15) * 8 + i0;
            short4v qh4, ql4, kh4, kl4;
            #pragma unroll
            for (int j = 0; j < 4; ++j) {
                const float qv = (t == 0 ? accQ0[i][j] : accQ1[i][j]) + bbq[j];
                const float kv = (t == 0 ? accK0[i][j] : accK1[i][j]) + bbk[j];
                unsigned short h, l;
                bf16_split(qv, h, l);
                qh4[j] = (short)h; ql4[j] = (short)l;
                bf16_split(kv, h, l);
                kh4[j] = (short)h; kl4[j] = (short)l;
            }
            *(short4v*)&Qh[addr] = qh4;
            *(short4v*)&Ql[addr] = ql4;
            *(short4v*)&Kh[addr] = kh4;
            *(short4v*)&Kl[addr] = kl4;
        }
    }
}

// ---------------------------------------------------------------------------
// Kernel B1 v19: batched score GEMM, 128x128 tiles (grid 2048).
// LDS stages 8 rt-segments per plane (32 KB); wave owns 2 row-groups x 8
// col-groups: per chunk per wave = 20 ds_read_b128 + 48 MFMA (2x better
// staging:MFMA ratio than v18's 64x64 tile); A/B L2 traffic halved.
// Same (hh,hl,lh) MFMA sequence per acc element, same chunk order ->
// bit-identical scores.
// ---------------------------------------------------------------------------
__global__ __launch_bounds__(256, 3) void score_kernel(
    const unsigned short* __restrict__ Qh, const unsigned short* __restrict__ Ql,
    const unsigned short* __restrict__ Kh, const unsigned short* __restrict__ Kl,
    float* __restrict__ out)
{
    __shared__ __align__(16) unsigned short Ah[8][512];   // 8 KB each
    __shared__ __align__(16) unsigned short Al[8][512];
    __shared__ __align__(16) unsigned short Bh[8][512];
    __shared__ __align__(16) unsigned short Bl[8][512];

    const int tid  = threadIdx.x;
    const int lane = tid & 63;
    const int w    = tid >> 6;        // 0..3
    const int lr   = lane & 15;
    const int lh   = lane >> 4;
    const int bid  = ((blockIdx.x & 7) << 8) + (blockIdx.x >> 3);  // XCD swz
    const int b    = bid >> 6;
    const int tr   = (bid >> 3) & 7;
    const int tc   = bid & 7;

    const int rtA0 = (b << 6) + (tr << 3);
    const int rtB0 = (b << 6) + (tc << 3);

    // staging: thread stages 2 segments per plane: rt_s = (tid>>6)+4s
    const int srt = tid >> 6;             // 0..3
    const int sln = tid & 63;
    const size_t sOff = (size_t)sln * 8;

    f32x4 acc[2][8];
    #pragma unroll
    for (int i = 0; i < 2; ++i)
        #pragma unroll
        for (int ct = 0; ct < 8; ++ct) acc[i][ct] = (f32x4){0.f, 0.f, 0.f, 0.f};

    uint4 pAh[2], pAl[2], pBh[2], pBl[2];
    #pragma unroll
    for (int s = 0; s < 2; ++s) {
        const size_t aAddr = (size_t)(rtA0 + srt + (s << 2)) * 4096 + sOff;
        const size_t bAddr = (size_t)(rtB0 + srt + (s << 2)) * 4096 + sOff;
        pAh[s] = *(const uint4*)(Qh + aAddr);
        pAl[s] = *(const uint4*)(Ql + aAddr);
        pBh[s] = *(const uint4*)(Kh + bAddr);
        pBl[s] = *(const uint4*)(Kl + bAddr);
    }

    #pragma unroll 1
    for (int c = 0; c < 8; ++c) {
        __syncthreads();              // previous chunk's LDS reads complete
        #pragma unroll
        for (int s = 0; s < 2; ++s) {
            *(uint4*)&Ah[srt + (s << 2)][sln << 3] = pAh[s];
            *(uint4*)&Al[srt + (s << 2)][sln << 3] = pAl[s];
            *(uint4*)&Bh[srt + (s << 2)][sln << 3] = pBh[s];
            *(uint4*)&Bl[srt + (s << 2)][sln << 3] = pBl[s];
        }
        __syncthreads();

        if (c < 7) {                  // prefetch next chunk (overlaps compute)
            const size_t cOff = (size_t)(c + 1) * 512;
            #pragma unroll
            for (int s = 0; s < 2; ++s) {
                const size_t aAddr = (size_t)(rtA0 + srt + (s << 2)) * 4096 + cOff + sOff;
                const size_t bAddr = (size_t)(rtB0 + srt + (s << 2)) * 4096 + cOff + sOff;
                pAh[s] = *(const uint4*)(Qh + aAddr);
                pAl[s] = *(const uint4*)(Ql + aAddr);
                pBh[s] = *(const uint4*)(Kh + bAddr);
                pBl[s] = *(const uint4*)(Kl + bAddr);
            }
        }

        // ---- A fragments (wave's two row-groups 2w, 2w+1) ----
        union { bf16x8 v; uint4 u; } aqh[2], aql[2];
        #pragma unroll
        for (int i = 0; i < 2; ++i) {
            aqh[i].u = *(const uint4*)&Ah[(w << 1) + i][lane << 3];
            aql[i].u = *(const uint4*)&Al[(w << 1) + i][lane << 3];
        }

        #pragma unroll
        for (int ct = 0; ct < 8; ++ct) {
            union { bf16x8 v; uint4 u; } kh_, kl_;
            kh_.u = *(const uint4*)&Bh[ct][lane << 3];
            kl_.u = *(const uint4*)&Bl[ct][lane << 3];
            #pragma unroll
            for (int i = 0; i < 2; ++i) {
                acc[i][ct] = __builtin_amdgcn_mfma_f32_16x16x32_bf16(aqh[i].v, kh_.v, acc[i][ct], 0, 0, 0);
                acc[i][ct] = __builtin_amdgcn_mfma_f32_16x16x32_bf16(aqh[i].v, kl_.v, acc[i][ct], 0, 0, 0);
                acc[i][ct] = __builtin_amdgcn_mfma_f32_16x16x32_bf16(aql[i].v, kh_.v, acc[i][ct], 0, 0, 0);
            }
        }
    }

    // D layout (hw-verified): tile row = lh*4 + reg, tile col = lr.
    #pragma unroll
    for (int i = 0; i < 2; ++i) {
        const int orow = (b << 10) + ((tr << 3) + (w << 1) + i) * 16 + (lh << 2);
        #pragma unroll
        for (int ct = 0; ct < 8; ++ct) {
            const int ocol = (tc << 7) + (ct << 4) + lr;
            float* op = out + (size_t)orow * 1024 + ocol;
            op[0]            = acc[i][ct].x;
            op[(size_t)1024] = acc[i][ct].y;
            op[(size_t)2048] = acc[i][ct].z;
            op[(size_t)3072] = acc[i][ct].w;
        }
    }
}

// ---------------------------------------------------------------------------
// Kernel B2 (v13 verbatim): softmax + top-16, in-place on out.
// ---------------------------------------------------------------------------
__global__ __launch_bounds__(256, 4) void topk_kernel(float* __restrict__ out)
{
    const int tid  = threadIdx.x;
    const int lane = tid & 63;
    const int w    = tid >> 6;
    const int rowBase = (int)(blockIdx.x << 3);

    float* __restrict__ r0p = out + (size_t)(rowBase + (w << 1) + 0) * 1024;
    float* __restrict__ r1p = out + (size_t)(rowBase + (w << 1) + 1) * 1024;

    float s0[16], s1[16];
    #pragma unroll
    for (int o = 0; o < 4; ++o) {
        const float4 a = *(const float4*)&r0p[(o << 8) + (lane << 2)];
        const float4 c = *(const float4*)&r1p[(o << 8) + (lane << 2)];
        s0[(o << 2) + 0] = a.x * 0.0625f;
        s0[(o << 2) + 1] = a.y * 0.0625f;
        s0[(o << 2) + 2] = a.z * 0.0625f;
        s0[(o << 2) + 3] = a.w * 0.0625f;
        s1[(o << 2) + 0] = c.x * 0.0625f;
        s1[(o << 2) + 1] = c.y * 0.0625f;
        s1[(o << 2) + 2] = c.z * 0.0625f;
        s1[(o << 2) + 3] = c.w * 0.0625f;
    }

    // row max (wave butterfly), both rows interleaved
    float mx0 = s0[0], mx1 = s1[0];
    #pragma unroll
    for (int i = 1; i < 16; ++i) {
        mx0 = fmaxf(mx0, s0[i]);
        mx1 = fmaxf(mx1, s1[i]);
    }
    #pragma unroll
    for (int off = 32; off > 0; off >>= 1) {
        mx0 = fmaxf(mx0, __shfl_xor(mx0, off));
        mx1 = fmaxf(mx1, __shfl_xor(mx1, off));
    }

    // softmax denominator
    float ls0 = 0.f, ls1 = 0.f;
    #pragma unroll
    for (int i = 0; i < 16; ++i) {
        ls0 += __expf(s0[i] - mx0);
        ls1 += __expf(s1[i] - mx1);
    }
    #pragma unroll
    for (int off = 32; off > 0; off >>= 1) {
        ls0 += __shfl_xor(ls0, off);
        ls1 += __shfl_xor(ls1, off);
    }
    const float rZ0 = 1.0f / ls0;
    const float rZ1 = 1.0f / ls1;

    // top-16 extraction on working copies; winners -> bitmasks
    float wv0[16], wv1[16];
    #pragma unroll
    for (int i = 0; i < 16; ++i) { wv0[i] = s0[i]; wv1[i] = s1[i]; }
    unsigned mask0 = 0u, mask1 = 0u;

    #pragma unroll 1
    for (int j = 0; j < KNNK; ++j) {
        float bv0 = wv0[0], bv1 = wv1[0];
        int   bi0 = 0,      bi1 = 0;
        #pragma unroll
        for (int i = 1; i < 16; ++i) {
            const bool c0 = wv0[i] > bv0;   // strict >, ascending slot scan
            bv0 = c0 ? wv0[i] : bv0;
            bi0 = c0 ? i      : bi0;
            const bool c1 = wv1[i] > bv1;
            bv1 = c1 ? wv1[i] : bv1;
            bi1 = c1 ? i      : bi1;
        }
        const int bm0 = ((bi0 >> 2) << 8) + (lane << 2) + (bi0 & 3);
        const int bm1 = ((bi1 >> 2) << 8) + (lane << 2) + (bi1 & 3);
        const unsigned ub0   = __float_as_uint(bv0);
        const unsigned ub1   = __float_as_uint(bv1);
        const unsigned mono0 = ub0 ^ (unsigned)(((int)ub0 >> 31) | 0x80000000);
        const unsigned mono1 = ub1 ^ (unsigned)(((int)ub1 >> 31) | 0x80000000);
        const unsigned long long key0 =
            ((unsigned long long)mono0 << 32) | (unsigned)(~bm0);
        const unsigned long long key1 =
            ((unsigned long long)mono1 << 32) | (unsigned)(~bm1);
        unsigned long long gk0 = key0, gk1 = key1;
        #pragma unroll
        for (int off = 32; off > 0; off >>= 1) {
            const unsigned long long o0 = __shfl_xor(gk0, off);
            const unsigned long long o1 = __shfl_xor(gk1, off);
            gk0 = (o0 > gk0) ? o0 : gk0;
            gk1 = (o1 > gk1) ? o1 : gk1;
        }
        if (key0 == gk0) {               // unique winner lane, row 0
            mask0 |= (1u << bi0);
            #pragma unroll
            for (int i = 0; i < 16; ++i)
                wv0[i] = (i == bi0) ? -__builtin_inff() : wv0[i];
        }
        if (key1 == gk1) {               // unique winner lane, row 1
            mask1 |= (1u << bi1);
            #pragma unroll
            for (int i = 0; i < 16; ++i)
                wv1[i] = (i == bi1) ? -__builtin_inff() : wv1[i];
        }
    }

    // full-coverage coalesced writes from pristine s0/s1
    #pragma unroll
    for (int o = 0; o < 4; ++o) {
        float4 v;
        v.x = ((mask0 >> ((o << 2) + 0)) & 1u) ? __expf(s0[(o << 2) + 0] - mx0) * rZ0 : 0.f;
        v.y = ((mask0 >> ((o << 2) + 1)) & 1u) ? __expf(s0[(o << 2) + 1] - mx0) * rZ0 : 0.f;
        v.z = ((mask0 >> ((o << 2) + 2)) & 1u) ? __expf(s0[(o << 2) + 2] - mx0) * rZ0 : 0.f;
        v.w = ((mask0 >> ((o << 2) + 3)) & 1u) ? __expf(s0[(o << 2) + 3] - mx0) * rZ0 : 0.f;
        *(float4*)&r0p[(lane << 2) + (o << 8)] = v;
    }
    #pragma unroll
    for (int o = 0; o < 4; ++o) {
        float4 v;
        v.x = ((mask1 >> ((o << 2) + 0)) & 1u) ? __expf(s1[(o << 2) + 0] - mx1) * rZ1 : 0.f;
        v.y = ((mask1 >> ((o << 2) + 1)) & 1u) ? __expf(s1[(o << 2) + 1] - mx1) * rZ1 : 0.f;
        v.z = ((mask1 >> ((o << 2) + 2)) & 1u) ? __expf(s1[(o << 2) + 2] - mx1) * rZ1 : 0.f;
        v.w = ((mask1 >> ((o << 2) + 3)) & 1u) ? __expf(s1[(o << 2) + 3] - mx1) * rZ1 : 0.f;
        *(float4*)&r1p[(lane << 2) + (o << 8)] = v;
    }
}

extern "C" void kernel_launch(void* const* d_in, const int* in_sizes, int n_in,
                              void* d_out, int out_size, void* d_ws, size_t ws_size,
                              hipStream_t stream)
{
    const float* x   = (const float*)d_in[0];
    const float* pos = (const float*)d_in[1];
    const float* wq  = (const float*)d_in[2];
    const float* bq  = (const float*)d_in[3];
    const float* wk  = (const float*)d_in[4];
    const float* bk  = (const float*)d_in[5];
    float* out = (float*)d_out;

    const size_t PLANE = (size_t)NB * NN * ND;       // 8M shorts = 16 MiB
    unsigned short* Qh = (unsigned short*)d_ws;
    unsigned short* Ql = Qh + PLANE;
    unsigned short* Kh = Ql + PLANE;
    unsigned short* Kl = Kh + PLANE;

    proj_kernel<<<dim3(1024), dim3(256), 0, stream>>>(x, pos, wq, bq, wk, bk,
                                                      Qh, Ql, Kh, Kl);
    score_kernel<<<dim3(2048), dim3(256), 0, stream>>>(Qh, Ql, Kh, Kl, out);
    topk_kernel<<<dim3(4096), dim3(256), 0, stream>>>(out);
}